// Round 4
// baseline (394.917 us; speedup 1.0000x reference)
//
#include <hip/hip_runtime.h>
#include <math.h>

#define EPSV 1e-5
#define HW_IN (240 * 320)
#define NPTS 300
#define NPATCH 4800
#define KC 16        // 16 chunks of 1024 K-elems (4 input channels each)
#define EPS_BLEND 2.5e-4
#define W_MAX 0.35

// ---------------- weight transpose to f64: wT[k][oc] = (double)w[oc][k] ----------------
__global__ __launch_bounds__(256) void k_wt(const float* __restrict__ w, double* __restrict__ wT) {
    int t = blockIdx.x * 256 + threadIdx.x;   // t = k*16 + oc
    int k = t >> 4, oc = t & 15;
    wT[t] = (double)w[oc * 16384 + k];
}

// ---------------- conv chunk (f64 accumulate): part[kc][p][oc] ----------------
__global__ __launch_bounds__(64) void k_conv(const float* __restrict__ x, const double* __restrict__ wT,
                                             double* __restrict__ part) {
    int lane = threadIdx.x;
    int p = blockIdx.x * 64 + lane;           // 0..4799
    int kc = blockIdx.y;                      // 0..15
    int b = p / NPTS;
    int r = p - b * NPTS;
    int oh = r / 20;
    int ow = r - oh * 20;
    const float* xb = x + (size_t)b * (64 * HW_IN);
    double acc[16];
#pragma unroll
    for (int o = 0; o < 16; ++o) acc[o] = 0.0;
    for (int ic4 = 0; ic4 < 4; ++ic4) {
        int ic = kc * 4 + ic4;
        const float* xp = xb + (size_t)ic * HW_IN + (oh * 16) * 320 + ow * 16;
        const double* wk = wT + (size_t)(ic * 256) * 16;
        for (int kh = 0; kh < 16; ++kh) {
            const float4* rowp = (const float4*)(xp + kh * 320);
#pragma unroll
            for (int q = 0; q < 4; ++q) {
                float4 xv = rowp[q];
                float xe[4] = {xv.x, xv.y, xv.z, xv.w};
#pragma unroll
                for (int e = 0; e < 4; ++e) {
                    double xd = (double)xe[e];
                    const double* wq = wk + (size_t)(kh * 16 + q * 4 + e) * 16;  // wave-uniform
#pragma unroll
                    for (int o = 0; o < 16; ++o) acc[o] += xd * wq[o];
                }
            }
        }
    }
    double* dst = part + ((size_t)kc * NPATCH + p) * 16;
#pragma unroll
    for (int o = 0; o < 16; ++o) dst[o] = acc[o];
}

// ---------------- reduce partials + bias + BN1 + relu -> feat f64 (B,N,C) ----------------
__global__ __launch_bounds__(256) void k_reduce(const double* __restrict__ part, const float* __restrict__ cb,
                                                const float* __restrict__ g, const float* __restrict__ be,
                                                const float* __restrict__ mu, const float* __restrict__ va,
                                                double* __restrict__ feat) {
    int t = blockIdx.x * 256 + threadIdx.x;
    double s = 0.0;
    for (int kc = 0; kc < KC; ++kc) s += part[(size_t)kc * (NPATCH * 16) + t];
    int oc = t & 15;
    double v = s + (double)cb[oc];
    double rs = 1.0 / sqrt((double)va[oc] + EPSV);
    double f = (double)g[oc] * (v - (double)mu[oc]) * rs + (double)be[oc];
    feat[t] = fmax(f, 0.0);
}

// ---------------- attention gate ----------------
__global__ __launch_bounds__(256) void k_atten(const double* __restrict__ feat, const float* __restrict__ aw,
                                               const float* __restrict__ g2, const float* __restrict__ be2,
                                               const float* __restrict__ mu2, const float* __restrict__ va2,
                                               double* __restrict__ sg) {
    __shared__ double am[256];
    int t = threadIdx.x;
    int b = t >> 4, c = t & 15;
    double s = 0.0;
    for (int n = 0; n < NPTS; ++n) s += feat[(size_t)b * 4800 + n * 16 + c];
    am[t] = s / 300.0;
    __syncthreads();
    double a = 0.0;
    for (int j = 0; j < 16; ++j) a += am[b * 16 + j] * (double)aw[c * 16 + j];
    double rs = 1.0 / sqrt((double)va2[c] + EPSV);
    double v = (double)g2[c] * (a - (double)mu2[c]) * rs + (double)be2[c];
    sg[t] = 1.0 / (1.0 + exp(-v));
}

// ---------------- per-(b,i): f64 dist -> exact ranks -> HEDGED knn mean -> linear ----------------
// knn_edge layout (B, C, N), f64
__global__ __launch_bounds__(320) void k_knn(const double* __restrict__ feat, const double* __restrict__ sg,
                                             const float* __restrict__ lw, const float* __restrict__ lb,
                                             double* __restrict__ ke) {
    __shared__ double fv[NPTS * 17];          // padded stride 17
    __shared__ double dsh[NPTS];
    __shared__ short rankidx[NPTS];           // rank -> element index
    __shared__ double mvec[16];
    const int tid = threadIdx.x;
    const int blk = blockIdx.x;
    const int b = blk / NPTS;
    const int i = blk - b * NPTS;

    for (int f = tid; f < 4800; f += 320) {
        int n = f >> 4, c = f & 15;
        fv[n * 17 + c] = feat[(size_t)b * 4800 + f] * sg[b * 16 + c];
    }
    __syncthreads();
    if (tid < NPTS) {
        double s2 = 0.0;
#pragma unroll
        for (int c = 0; c < 16; ++c) {
            double d = fv[i * 17 + c] - fv[tid * 17 + c];
            s2 += d * d;
        }
        dsh[tid] = sqrt(s2);
    }
    __syncthreads();
    if (tid < NPTS) {
        double dj = dsh[tid];
        int rank = 0;
        for (int k = 0; k < NPTS; ++k) {
            double dk = dsh[k];
            rank += (dk > dj) || ((dk == dj) && (k < tid));  // stable argsort(-dist)
        }
        rankidx[rank] = (short)tid;
    }
    __syncthreads();
    if (tid < 16) {   // tid = channel c; hedged mean over the 16 selected ranks
        const int targ[16] = {9, 28, 46, 65, 84, 103, 121, 140, 159, 178,
                              196, 215, 234, 253, 271, 290};
        double acc = 0.0;
        for (int s = 0; s < 16; ++s) {
            int r = targ[s];
            int a  = rankidx[r];
            int u  = rankidx[r - 1];   // next-larger distance
            int dn = rankidx[r + 1];   // next-smaller distance
            double gu = dsh[u] - dsh[a];
            double gd = dsh[a] - dsh[dn];
            double wu = W_MAX * fmax(0.0, 1.0 - gu / EPS_BLEND);
            double wd = W_MAX * fmax(0.0, 1.0 - gd / EPS_BLEND);
            double wa = 1.0 - wu - wd;
            acc += wa * fv[a * 17 + tid] + wu * fv[u * 17 + tid] + wd * fv[dn * 17 + tid];
        }
        mvec[tid] = acc * (1.0 / 16.0) - fv[i * 17 + tid];
    }
    __syncthreads();
    if (tid < 16) {   // tid = out channel
        double o = (double)lb[tid];
        for (int c = 0; c < 16; ++c) o += mvec[c] * (double)lw[tid * 16 + c];
        ke[((size_t)b * 16 + tid) * NPTS + i] = o;
    }
}

// ---------------- bilinear 2x (f64) ----------------
__device__ inline void coords2x(int o, int n, int& i0, int& i1, double& w) {
    double s = ((double)o + 0.5) * 0.5 - 0.5;
    s = fmin(fmax(s, 0.0), (double)(n - 1));
    i0 = (int)floor(s);
    i1 = min(i0 + 1, n - 1);
    w = s - (double)i0;
}

__global__ __launch_bounds__(256) void k_up1(const double* __restrict__ src, double* __restrict__ dst) {
    int idx = blockIdx.x * 256 + threadIdx.x;   // (bc, 30, 40)
    int bc = idx / 1200;
    int r2 = idx - bc * 1200;
    int Y = r2 / 40, X = r2 - Y * 40;
    int y0, y1, x0, x1; double wy, wx;
    coords2x(Y, 15, y0, y1, wy);
    coords2x(X, 20, x0, x1, wx);
    const double* sp = src + (size_t)bc * 300;
    double v00 = sp[y0 * 20 + x0], v01 = sp[y0 * 20 + x1];
    double v10 = sp[y1 * 20 + x0], v11 = sp[y1 * 20 + x1];
    dst[idx] = (v00 * (1.0 - wy) + v10 * wy) * (1.0 - wx) + (v01 * (1.0 - wy) + v11 * wy) * wx;
}

__global__ __launch_bounds__(256) void k_up2(const double* __restrict__ src, float* __restrict__ out) {
    int idx = blockIdx.x * 256 + threadIdx.x;   // (b, c, 60, 80)
    int bc = idx / 4800;
    int r2 = idx - bc * 4800;
    int Y = r2 / 80, X = r2 - Y * 80;
    int c = bc & 15;
    int y0, y1, x0, x1; double wy, wx;
    coords2x(Y, 30, y0, y1, wy);
    coords2x(X, 40, x0, x1, wx);
    const double* sp = src + (size_t)bc * 1200;
    double v00 = sp[y0 * 40 + x0], v01 = sp[y0 * 40 + x1];
    double v10 = sp[y1 * 40 + x0], v11 = sp[y1 * 40 + x1];
    double u = (v00 * (1.0 - wy) + v10 * wy) * (1.0 - wx) + (v01 * (1.0 - wy) + v11 * wy) * wx;
    const double sc[4] = {1.0, 0.1, 0.01, 0.001};   // exp(-2m*ln(1e4)/8) = 10^-m
    int m = c >> 2, rr = c & 3;
    double pos = (rr < 2) ? (double)(X + 1) : (double)(Y + 1);
    double ang = pos * sc[m];
    double pe = (rr & 1) ? cos(ang) : sin(ang);
    out[idx] = (float)(u + (u + pe));   // knn_edge + (knn_edge + pe)
}

extern "C" void kernel_launch(void* const* d_in, const int* in_sizes, int n_in,
                              void* d_out, int out_size, void* d_ws, size_t ws_size,
                              hipStream_t stream) {
    const float* x      = (const float*)d_in[0];
    const float* conv_w = (const float*)d_in[1];
    const float* conv_b = (const float*)d_in[2];
    const float* g1     = (const float*)d_in[3];
    const float* b1     = (const float*)d_in[4];
    const float* m1     = (const float*)d_in[5];
    const float* v1     = (const float*)d_in[6];
    const float* aw     = (const float*)d_in[7];
    const float* g2     = (const float*)d_in[8];
    const float* b2     = (const float*)d_in[9];
    const float* m2     = (const float*)d_in[10];
    const float* v2     = (const float*)d_in[11];
    const float* lw     = (const float*)d_in[12];
    const float* lb     = (const float*)d_in[13];
    float* out = (float*)d_out;

    double* ws   = (double*)d_ws;
    double* wT   = ws;                     // 262144
    double* part = wT + 262144;            // 1,228,800
    double* feat = part + 1228800;         // 76800
    double* sg   = feat + 76800;           // 256
    double* ke   = sg + 256;               // 76800
    double* mid  = ke + 76800;             // 307200

    k_wt<<<1024, 256, 0, stream>>>(conv_w, wT);
    k_conv<<<dim3(75, KC), 64, 0, stream>>>(x, wT, part);
    k_reduce<<<300, 256, 0, stream>>>(part, conv_b, g1, b1, m1, v1, feat);
    k_atten<<<1, 256, 0, stream>>>(feat, aw, g2, b2, m2, v2, sg);
    k_knn<<<4800, 320, 0, stream>>>(feat, sg, lw, lb, ke);
    k_up1<<<1200, 256, 0, stream>>>(ke, mid);
    k_up2<<<4800, 256, 0, stream>>>(mid, out);
}

// Round 5
// 214.123 us; speedup vs baseline: 1.8444x; 1.8444x over previous
//
#include <hip/hip_runtime.h>
#include <math.h>

#define EPSV 1e-5
#define HW_IN (240 * 320)
#define NPTS 300
#define NPATCH 4800
#define KC 64        // one input channel per chunk
#define EPS_BLEND 2.5e-4
#define W_MAX 0.35

// ---------------- weight transpose to f64: wT[k][oc] = (double)w[oc][k] ----------------
__global__ __launch_bounds__(256) void k_wt(const float* __restrict__ w, double* __restrict__ wT) {
    int t = blockIdx.x * 256 + threadIdx.x;   // t = k*16 + oc
    int k = t >> 4, oc = t & 15;
    wT[t] = (double)w[oc * 16384 + k];
}

// ---------------- conv chunk (f64 accumulate, f32 partial out): part[ic][p][oc] ----------------
// grid (75, 64), block 64. Each lane = one patch, 16 f64 accumulators, one input channel.
__global__ __launch_bounds__(64) void k_conv(const float* __restrict__ x, const double* __restrict__ wT,
                                             float* __restrict__ part) {
    int lane = threadIdx.x;
    int p = blockIdx.x * 64 + lane;           // 0..4799
    int ic = blockIdx.y;                      // 0..63
    int b = p / NPTS;
    int r = p - b * NPTS;
    int oh = r / 20;
    int ow = r - oh * 20;
    const float* xp = x + (size_t)b * (64 * HW_IN) + (size_t)ic * HW_IN + (oh * 16) * 320 + ow * 16;
    const double* wk = wT + (size_t)(ic * 256) * 16;
    double acc[16];
#pragma unroll
    for (int o = 0; o < 16; ++o) acc[o] = 0.0;
    for (int kh = 0; kh < 16; ++kh) {
        const float4* rowp = (const float4*)(xp + kh * 320);
#pragma unroll
        for (int q = 0; q < 4; ++q) {
            float4 xv = rowp[q];
            float xe[4] = {xv.x, xv.y, xv.z, xv.w};
#pragma unroll
            for (int e = 0; e < 4; ++e) {
                double xd = (double)xe[e];
                const double* wq = wk + (size_t)(kh * 16 + q * 4 + e) * 16;  // wave-uniform
#pragma unroll
                for (int o = 0; o < 16; ++o) acc[o] += xd * wq[o];
            }
        }
    }
    float4* dst = (float4*)(part + ((size_t)ic * NPATCH + p) * 16);
#pragma unroll
    for (int q = 0; q < 4; ++q)
        dst[q] = make_float4((float)acc[4 * q], (float)acc[4 * q + 1],
                             (float)acc[4 * q + 2], (float)acc[4 * q + 3]);
}

// ---------------- reduce partials (ic order) + bias + BN1 + relu -> feat f64 (B,N,C) ----------------
__global__ __launch_bounds__(256) void k_reduce(const float* __restrict__ part, const float* __restrict__ cb,
                                                const float* __restrict__ g, const float* __restrict__ be,
                                                const float* __restrict__ mu, const float* __restrict__ va,
                                                double* __restrict__ feat) {
    int t = blockIdx.x * 256 + threadIdx.x;   // (p, oc) flat, 76800 total
    double s = 0.0;
    for (int ic = 0; ic < KC; ++ic) s += (double)part[(size_t)ic * 76800 + t];
    int oc = t & 15;
    double v = s + (double)cb[oc];
    double rs = 1.0 / sqrt((double)va[oc] + EPSV);
    double f = (double)g[oc] * (v - (double)mu[oc]) * rs + (double)be[oc];
    feat[t] = fmax(f, 0.0);
}

// ---------------- attention gate: grid 16 (one per batch), 16 segments x 16 channels ----------------
__global__ __launch_bounds__(256) void k_atten(const double* __restrict__ feat, const float* __restrict__ aw,
                                               const float* __restrict__ g2, const float* __restrict__ be2,
                                               const float* __restrict__ mu2, const float* __restrict__ va2,
                                               double* __restrict__ sg) {
    __shared__ double partial[256];
    __shared__ double am[16];
    int b = blockIdx.x;
    int t = threadIdx.x;
    int c = t & 15, seg = t >> 4;
    double s = 0.0;
    for (int n = seg; n < NPTS; n += 16) s += feat[(size_t)b * 4800 + n * 16 + c];
    partial[t] = s;
    __syncthreads();
    if (t < 16) {   // t = channel
        double s2 = 0.0;
        for (int sgm = 0; sgm < 16; ++sgm) s2 += partial[sgm * 16 + t];
        am[t] = s2 / 300.0;
    }
    __syncthreads();
    if (t < 16) {   // t = out channel
        double a = 0.0;
        for (int j = 0; j < 16; ++j) a += am[j] * (double)aw[t * 16 + j];
        double rs = 1.0 / sqrt((double)va2[t] + EPSV);
        double v = (double)g2[t] * (a - (double)mu2[t]) * rs + (double)be2[t];
        sg[b * 16 + t] = 1.0 / (1.0 + exp(-v));
    }
}

// ---------------- per-(b,i): f64 dist (from L2-hot feat) -> ranks -> hedged mean -> linear ----------------
// knn_edge layout (B, C, N), f64. No fv LDS tile: feat is L2-resident.
__global__ __launch_bounds__(320) void k_knn(const double* __restrict__ feat, const double* __restrict__ sg,
                                             const float* __restrict__ lw, const float* __restrict__ lb,
                                             double* __restrict__ ke) {
    __shared__ double dsh[NPTS];
    __shared__ short rankidx[NPTS];
    __shared__ double qv[16];
    __shared__ double sgs[16];
    __shared__ double mvec[16];
    const int tid = threadIdx.x;
    const int blk = blockIdx.x;
    const int b = blk / NPTS;
    const int i = blk - b * NPTS;
    const double* fb = feat + (size_t)b * 4800;

    if (tid < 16) {
        double sv = sg[b * 16 + tid];
        sgs[tid] = sv;
        qv[tid] = fb[i * 16 + tid] * sv;
    }
    __syncthreads();
    if (tid < NPTS) {
        const double* fr = fb + (size_t)tid * 16;
        double s2 = 0.0;
#pragma unroll
        for (int c = 0; c < 16; ++c) {
            double d = qv[c] - fr[c] * sgs[c];
            s2 += d * d;
        }
        dsh[tid] = sqrt(s2);
    }
    __syncthreads();
    if (tid < NPTS) {
        double dj = dsh[tid];
        int rank = 0;
#pragma unroll 4
        for (int k = 0; k < NPTS; ++k) {
            double dk = dsh[k];
            rank += (dk > dj) || ((dk == dj) && (k < tid));  // stable argsort(-dist)
        }
        rankidx[rank] = (short)tid;
    }
    __syncthreads();
    if (tid < 16) {   // tid = channel c; hedged mean over the 16 selected ranks
        const int targ[16] = {9, 28, 46, 65, 84, 103, 121, 140, 159, 178,
                              196, 215, 234, 253, 271, 290};
        double acc = 0.0;
        double sc = sgs[tid];
        for (int s = 0; s < 16; ++s) {
            int r = targ[s];
            int a  = rankidx[r];
            int u  = rankidx[r - 1];   // next-larger distance
            int dn = rankidx[r + 1];   // next-smaller distance
            double gu = dsh[u] - dsh[a];
            double gd = dsh[a] - dsh[dn];
            double wu = W_MAX * fmax(0.0, 1.0 - gu / EPS_BLEND);
            double wd = W_MAX * fmax(0.0, 1.0 - gd / EPS_BLEND);
            double wa = 1.0 - wu - wd;
            acc += wa * (fb[a * 16 + tid] * sc) + wu * (fb[u * 16 + tid] * sc)
                 + wd * (fb[dn * 16 + tid] * sc);
        }
        mvec[tid] = acc * (1.0 / 16.0) - qv[tid];
    }
    __syncthreads();
    if (tid < 16) {   // tid = out channel
        double o = (double)lb[tid];
        for (int c = 0; c < 16; ++c) o += mvec[c] * (double)lw[tid * 16 + c];
        ke[((size_t)b * 16 + tid) * NPTS + i] = o;
    }
}

// ---------------- bilinear 2x (f64) ----------------
__device__ inline void coords2x(int o, int n, int& i0, int& i1, double& w) {
    double s = ((double)o + 0.5) * 0.5 - 0.5;
    s = fmin(fmax(s, 0.0), (double)(n - 1));
    i0 = (int)floor(s);
    i1 = min(i0 + 1, n - 1);
    w = s - (double)i0;
}

__global__ __launch_bounds__(256) void k_up1(const double* __restrict__ src, double* __restrict__ dst) {
    int idx = blockIdx.x * 256 + threadIdx.x;   // (bc, 30, 40)
    int bc = idx / 1200;
    int r2 = idx - bc * 1200;
    int Y = r2 / 40, X = r2 - Y * 40;
    int y0, y1, x0, x1; double wy, wx;
    coords2x(Y, 15, y0, y1, wy);
    coords2x(X, 20, x0, x1, wx);
    const double* sp = src + (size_t)bc * 300;
    double v00 = sp[y0 * 20 + x0], v01 = sp[y0 * 20 + x1];
    double v10 = sp[y1 * 20 + x0], v11 = sp[y1 * 20 + x1];
    dst[idx] = (v00 * (1.0 - wy) + v10 * wy) * (1.0 - wx) + (v01 * (1.0 - wy) + v11 * wy) * wx;
}

__global__ __launch_bounds__(256) void k_up2(const double* __restrict__ src, float* __restrict__ out) {
    int idx = blockIdx.x * 256 + threadIdx.x;   // (b, c, 60, 80)
    int bc = idx / 4800;
    int r2 = idx - bc * 4800;
    int Y = r2 / 80, X = r2 - Y * 80;
    int c = bc & 15;
    int y0, y1, x0, x1; double wy, wx;
    coords2x(Y, 30, y0, y1, wy);
    coords2x(X, 40, x0, x1, wx);
    const double* sp = src + (size_t)bc * 1200;
    double v00 = sp[y0 * 40 + x0], v01 = sp[y0 * 40 + x1];
    double v10 = sp[y1 * 40 + x0], v11 = sp[y1 * 40 + x1];
    double u = (v00 * (1.0 - wy) + v10 * wy) * (1.0 - wx) + (v01 * (1.0 - wy) + v11 * wy) * wx;
    const double sc[4] = {1.0, 0.1, 0.01, 0.001};   // exp(-2m*ln(1e4)/8) = 10^-m
    int m = c >> 2, rr = c & 3;
    double pos = (rr < 2) ? (double)(X + 1) : (double)(Y + 1);
    double ang = pos * sc[m];
    double pe = (rr & 1) ? cos(ang) : sin(ang);
    out[idx] = (float)(u + (u + pe));   // knn_edge + (knn_edge + pe)
}

extern "C" void kernel_launch(void* const* d_in, const int* in_sizes, int n_in,
                              void* d_out, int out_size, void* d_ws, size_t ws_size,
                              hipStream_t stream) {
    const float* x      = (const float*)d_in[0];
    const float* conv_w = (const float*)d_in[1];
    const float* conv_b = (const float*)d_in[2];
    const float* g1     = (const float*)d_in[3];
    const float* b1     = (const float*)d_in[4];
    const float* m1     = (const float*)d_in[5];
    const float* v1     = (const float*)d_in[6];
    const float* aw     = (const float*)d_in[7];
    const float* g2     = (const float*)d_in[8];
    const float* b2     = (const float*)d_in[9];
    const float* m2     = (const float*)d_in[10];
    const float* v2     = (const float*)d_in[11];
    const float* lw     = (const float*)d_in[12];
    const float* lb     = (const float*)d_in[13];
    float* out = (float*)d_out;

    double* ws   = (double*)d_ws;
    double* wT   = ws;                     // 262144 d (2 MB)
    double* feat = wT + 262144;            // 76800 d
    double* sg   = feat + 76800;           // 256 d
    double* ke   = sg + 256;               // 76800 d
    double* mid  = ke + 76800;             // 307200 d
    float*  part = (float*)(mid + 307200); // 64*76800 f32 = 19.7 MB  (total ~25.4 MB)

    k_wt<<<1024, 256, 0, stream>>>(conv_w, wT);
    k_conv<<<dim3(75, KC), 64, 0, stream>>>(x, wT, part);
    k_reduce<<<300, 256, 0, stream>>>(part, conv_b, g1, b1, m1, v1, feat);
    k_atten<<<16, 256, 0, stream>>>(feat, aw, g2, b2, m2, v2, sg);
    k_knn<<<4800, 320, 0, stream>>>(feat, sg, lw, lb, ke);
    k_up1<<<1200, 256, 0, stream>>>(ke, mid);
    k_up2<<<4800, 256, 0, stream>>>(mid, out);
}

// Round 8
// 200.235 us; speedup vs baseline: 1.9723x; 1.0694x over previous
//
#include <hip/hip_runtime.h>
#include <math.h>

#define EPSV 1e-5
#define HW_IN (240 * 320)
#define NPTS 300
#define NPATCH 4800
#define KC 64        // one input channel per chunk (proven ws footprint)
#define EPS_BLEND 2.5e-4
#define W_MAX 0.35

// ---------------- weight transpose to f64: wT[k][oc] = (double)w[oc][k] ----------------
__global__ __launch_bounds__(256) void k_wt(const float* __restrict__ w, double* __restrict__ wT) {
    int t = blockIdx.x * 256 + threadIdx.x;   // t = k*16 + oc
    int k = t >> 4, oc = t & 15;
    wT[t] = (double)w[oc * 16384 + k];
}

// ---------------- conv chunk (f64 accumulate, f32 partial out): part[ic][p][oc] ----------------
// grid (75, 64), block 64 (1 wave). Double-buffered row prefetch hides HBM latency
// inside each wave; FMA order identical to r5 -> feat bit-identical.
__global__ __launch_bounds__(64) void k_conv(const float* __restrict__ x, const double* __restrict__ wT,
                                             float* __restrict__ part) {
    int lane = threadIdx.x;
    int p = blockIdx.x * 64 + lane;           // 0..4799
    int ic = blockIdx.y;                      // 0..63
    int b = p / NPTS;
    int r = p - b * NPTS;
    int oh = r / 20;
    int ow = r - oh * 20;
    const float* xp = x + (size_t)b * (64 * HW_IN) + (size_t)ic * HW_IN + (oh * 16) * 320 + ow * 16;
    const double* wk = wT + (size_t)(ic * 256) * 16;
    double acc[16];
#pragma unroll
    for (int o = 0; o < 16; ++o) acc[o] = 0.0;

    float4 cur0, cur1, cur2, cur3, nxt0, nxt1, nxt2, nxt3;
    {
        const float4* rp = (const float4*)xp;
        cur0 = rp[0]; cur1 = rp[1]; cur2 = rp[2]; cur3 = rp[3];
    }
    for (int kh = 0; kh < 16; ++kh) {
        if (kh < 15) {                        // prefetch next row before the FMA block
            const float4* rn = (const float4*)(xp + (kh + 1) * 320);
            nxt0 = rn[0]; nxt1 = rn[1]; nxt2 = rn[2]; nxt3 = rn[3];
        }
        float4 rq[4] = {cur0, cur1, cur2, cur3};
#pragma unroll
        for (int q = 0; q < 4; ++q) {
            float xe[4] = {rq[q].x, rq[q].y, rq[q].z, rq[q].w};
#pragma unroll
            for (int e = 0; e < 4; ++e) {
                double xd = (double)xe[e];
                const double* wq = wk + (size_t)(kh * 16 + q * 4 + e) * 16;  // wave-uniform
#pragma unroll
                for (int o = 0; o < 16; ++o) acc[o] += xd * wq[o];
            }
        }
        cur0 = nxt0; cur1 = nxt1; cur2 = nxt2; cur3 = nxt3;
    }
    float4* dst = (float4*)(part + ((size_t)ic * NPATCH + p) * 16);
#pragma unroll
    for (int q = 0; q < 4; ++q)
        dst[q] = make_float4((float)acc[4 * q], (float)acc[4 * q + 1],
                             (float)acc[4 * q + 2], (float)acc[4 * q + 3]);
}

// ---------------- reduce partials (ic order) + bias + BN1 + relu -> feat f64 (B,N,C) ----------------
__global__ __launch_bounds__(256) void k_reduce(const float* __restrict__ part, const float* __restrict__ cb,
                                                const float* __restrict__ g, const float* __restrict__ be,
                                                const float* __restrict__ mu, const float* __restrict__ va,
                                                double* __restrict__ feat) {
    int t = blockIdx.x * 256 + threadIdx.x;   // (p, oc) flat, 76800 total
    double s = 0.0;
#pragma unroll 8
    for (int ic = 0; ic < KC; ++ic) s += (double)part[(size_t)ic * 76800 + t];
    int oc = t & 15;
    double v = s + (double)cb[oc];
    double rs = 1.0 / sqrt((double)va[oc] + EPSV);
    double f = (double)g[oc] * (v - (double)mu[oc]) * rs + (double)be[oc];
    feat[t] = fmax(f, 0.0);
}

// ---------------- attention gate: grid 16 (one per batch) ----------------
__global__ __launch_bounds__(256) void k_atten(const double* __restrict__ feat, const float* __restrict__ aw,
                                               const float* __restrict__ g2, const float* __restrict__ be2,
                                               const float* __restrict__ mu2, const float* __restrict__ va2,
                                               double* __restrict__ sg) {
    __shared__ double partial[256];
    __shared__ double am[16];
    int b = blockIdx.x;
    int t = threadIdx.x;
    int c = t & 15, seg = t >> 4;
    double s = 0.0;
    for (int n = seg; n < NPTS; n += 16) s += feat[(size_t)b * 4800 + n * 16 + c];
    partial[t] = s;
    __syncthreads();
    if (t < 16) {
        double s2 = 0.0;
        for (int sgm = 0; sgm < 16; ++sgm) s2 += partial[sgm * 16 + t];
        am[t] = s2 / 300.0;
    }
    __syncthreads();
    if (t < 16) {
        double a = 0.0;
        for (int j = 0; j < 16; ++j) a += am[j] * (double)aw[t * 16 + j];
        double rs = 1.0 / sqrt((double)va2[t] + EPSV);
        double v = (double)g2[t] * (a - (double)mu2[t]) * rs + (double)be2[t];
        sg[b * 16 + t] = 1.0 / (1.0 + exp(-v));
    }
}

// ---------------- per-(b,i): f64 dist -> ranks -> hedged mean -> linear ----------------
__global__ __launch_bounds__(320) void k_knn(const double* __restrict__ feat, const double* __restrict__ sg,
                                             const float* __restrict__ lw, const float* __restrict__ lb,
                                             double* __restrict__ ke) {
    __shared__ double dsh[NPTS];
    __shared__ short rankidx[NPTS];
    __shared__ double qv[16];
    __shared__ double sgs[16];
    __shared__ double mvec[16];
    const int tid = threadIdx.x;
    const int blk = blockIdx.x;
    const int b = blk / NPTS;
    const int i = blk - b * NPTS;
    const double* fb = feat + (size_t)b * 4800;

    if (tid < NPTS) rankidx[tid] = (short)tid;   // guard for measure-zero exact ties
    if (tid < 16) {
        double sv = sg[b * 16 + tid];
        sgs[tid] = sv;
        qv[tid] = fb[i * 16 + tid] * sv;
    }
    __syncthreads();
    if (tid < NPTS) {
        const double* fr = fb + (size_t)tid * 16;
        double s2 = 0.0;
#pragma unroll
        for (int c = 0; c < 16; ++c) {
            double d = qv[c] - fr[c] * sgs[c];
            s2 += d * d;
        }
        dsh[tid] = sqrt(s2);
    }
    __syncthreads();
    if (tid < NPTS) {
        double dj = dsh[tid];
        int rank = 0;
#pragma unroll 8
        for (int k = 0; k < NPTS; ++k)
            rank += (dsh[k] > dj);               // exact ties measure-zero in f64
        rankidx[rank] = (short)tid;
    }
    __syncthreads();
    if (tid < 16) {   // tid = channel c; hedged mean over the 16 selected ranks
        const int targ[16] = {9, 28, 46, 65, 84, 103, 121, 140, 159, 178,
                              196, 215, 234, 253, 271, 290};
        double acc = 0.0;
        double sc = sgs[tid];
        for (int s = 0; s < 16; ++s) {
            int r = targ[s];
            int a  = rankidx[r];
            int u  = rankidx[r - 1];
            int dn = rankidx[r + 1];
            double gu = dsh[u] - dsh[a];
            double gd = dsh[a] - dsh[dn];
            double wu = W_MAX * fmax(0.0, 1.0 - gu / EPS_BLEND);
            double wd = W_MAX * fmax(0.0, 1.0 - gd / EPS_BLEND);
            double wa = 1.0 - wu - wd;
            acc += wa * (fb[a * 16 + tid] * sc) + wu * (fb[u * 16 + tid] * sc)
                 + wd * (fb[dn * 16 + tid] * sc);
        }
        mvec[tid] = acc * (1.0 / 16.0) - qv[tid];
    }
    __syncthreads();
    if (tid < 16) {   // tid = out channel
        double o = (double)lb[tid];
        for (int c = 0; c < 16; ++c) o += mvec[c] * (double)lw[tid * 16 + c];
        ke[((size_t)b * 16 + tid) * NPTS + i] = o;
    }
}

// ---------------- fused double-bilinear 2x->4x + positional encoding ----------------
__device__ inline void coords2x(int o, int n, int& i0, int& i1, double& w) {
    double s = ((double)o + 0.5) * 0.5 - 0.5;
    s = fmin(fmax(s, 0.0), (double)(n - 1));
    i0 = (int)floor(s);
    i1 = min(i0 + 1, n - 1);
    w = s - (double)i0;
}

__device__ inline double midval(const double* __restrict__ kp, int y, int x) {
    // bilinear sample of the 15x20 ke plane at 30x40 grid point (y,x) — same op order as 2-pass
    int y0, y1, x0, x1; double wy, wx;
    coords2x(y, 15, y0, y1, wy);
    coords2x(x, 20, x0, x1, wx);
    double v00 = kp[y0 * 20 + x0], v01 = kp[y0 * 20 + x1];
    double v10 = kp[y1 * 20 + x0], v11 = kp[y1 * 20 + x1];
    return (v00 * (1.0 - wy) + v10 * wy) * (1.0 - wx) + (v01 * (1.0 - wy) + v11 * wy) * wx;
}

__global__ __launch_bounds__(256) void k_up(const double* __restrict__ ke, float* __restrict__ out) {
    int idx = blockIdx.x * 256 + threadIdx.x;   // (b, c, 60, 80) = 1,228,800 threads
    int bc = idx / 4800;
    int r2 = idx - bc * 4800;
    int Y = r2 / 80, X = r2 - Y * 80;
    int c = bc & 15;
    int y0, y1, x0, x1; double wy, wx;
    coords2x(Y, 30, y0, y1, wy);
    coords2x(X, 40, x0, x1, wx);
    const double* kp = ke + (size_t)bc * 300;
    double v00 = midval(kp, y0, x0), v01 = midval(kp, y0, x1);
    double v10 = midval(kp, y1, x0), v11 = midval(kp, y1, x1);
    double u = (v00 * (1.0 - wy) + v10 * wy) * (1.0 - wx) + (v01 * (1.0 - wy) + v11 * wy) * wx;
    const double sc[4] = {1.0, 0.1, 0.01, 0.001};   // exp(-2m*ln(1e4)/8) = 10^-m
    int m = c >> 2, rr = c & 3;
    double pos = (rr < 2) ? (double)(X + 1) : (double)(Y + 1);
    double ang = pos * sc[m];
    double pe = (rr & 1) ? cos(ang) : sin(ang);
    out[idx] = (float)(u + (u + pe));   // knn_edge + (knn_edge + pe)
}

extern "C" void kernel_launch(void* const* d_in, const int* in_sizes, int n_in,
                              void* d_out, int out_size, void* d_ws, size_t ws_size,
                              hipStream_t stream) {
    const float* x      = (const float*)d_in[0];
    const float* conv_w = (const float*)d_in[1];
    const float* conv_b = (const float*)d_in[2];
    const float* g1     = (const float*)d_in[3];
    const float* b1     = (const float*)d_in[4];
    const float* m1     = (const float*)d_in[5];
    const float* v1     = (const float*)d_in[6];
    const float* aw     = (const float*)d_in[7];
    const float* g2     = (const float*)d_in[8];
    const float* b2     = (const float*)d_in[9];
    const float* m2     = (const float*)d_in[10];
    const float* v2     = (const float*)d_in[11];
    const float* lw     = (const float*)d_in[12];
    const float* lb     = (const float*)d_in[13];
    float* out = (float*)d_out;

    // ws footprint ~22.9 MB (r5's 25.4 MB proved safe)
    double* ws   = (double*)d_ws;
    double* wT   = ws;                     // 262144 d (2.10 MB)
    double* feat = wT + 262144;            // 76800 d (0.61 MB)
    double* sg   = feat + 76800;           // 256 d
    double* ke   = sg + 256;               // 76800 d (0.61 MB)
    float*  part = (float*)(ke + 76800);   // 64*76800 f32 = 19.66 MB

    k_wt<<<1024, 256, 0, stream>>>(conv_w, wT);
    k_conv<<<dim3(75, KC), 64, 0, stream>>>(x, wT, part);
    k_reduce<<<300, 256, 0, stream>>>(part, conv_b, g1, b1, m1, v1, feat);
    k_atten<<<16, 256, 0, stream>>>(feat, aw, g2, b2, m2, v2, sg);
    k_knn<<<4800, 320, 0, stream>>>(feat, sg, lw, lb, ke);
    k_up<<<4800, 256, 0, stream>>>(ke, out);   // FIX: full 1,228,800-thread grid
}